// Round 2
// baseline (2062.381 us; speedup 1.0000x reference)
//
#include <hip/hip_runtime.h>
#include <math.h>

// Problem constants
#define B_    4
#define C_    64
#define S_    32768          // 32*32*32 spatial
#define N_    131072         // B_*S_ tokens
#define K_    512            // codebook size
#define DECAY_ 0.99f
#define ONEM_  0.01f         // 1-DECAY
#define ALPHA_ 1e-5f

// d_out layout (float32, concatenated in reference return order)
#define OFF_LOSS 0
#define OFF_Q    1
#define OFF_PERP 8388609
#define OFF_IDX  8388610
#define OFF_NEMB 8519682
#define OFF_NCS  8552450
#define OFF_NEA  8552962

// ws layout in 4-byte units
#define WS_LOSS   0
#define WS_CNT    16        // 512 ints
#define WS_SMOOTH 528       // 512 floats
#define WS_DW     1040      // 512*64 floats (atomic-accumulated dw)

// ---------------------------------------------------------------------------
// K1: per-token argmin over 512 codes, quantized write, loss partial,
//     LDS histogram of code usage.
// ---------------------------------------------------------------------------
__global__ __launch_bounds__(256) void k_assign(const float* __restrict__ in,
                                                const float* __restrict__ embed,
                                                float* __restrict__ out,
                                                float* __restrict__ wsf,
                                                int* __restrict__ wsi) {
    __shared__ float s_e2[K_];
    __shared__ int   s_cnt[K_];
    __shared__ float s_red[4];

    const int t = threadIdx.x;
    const int n = blockIdx.x * 256 + t;          // token id, channel-last order
    const int b = n >> 15;
    const int s = n & (S_ - 1);
    const int base = (b << 21) + s;              // element index at c=0

    float x[C_];
#pragma unroll
    for (int c = 0; c < C_; ++c) x[c] = in[base + (c << 15)];
    float x2 = 0.f;
#pragma unroll
    for (int c = 0; c < C_; ++c) x2 += x[c] * x[c];

    // cooperative: code norms into LDS, zero histogram
    for (int kk = t; kk < K_; kk += 256) {
        const float4* er = (const float4*)(embed + kk * C_);
        float e2 = 0.f;
#pragma unroll
        for (int q = 0; q < 16; ++q) {
            float4 v = er[q];
            e2 += v.x * v.x + v.y * v.y + v.z * v.z + v.w * v.w;
        }
        s_e2[kk] = e2;
        s_cnt[kk] = 0;
    }
    __syncthreads();

    float best = 3.4e38f;
    int bk = 0;
#pragma unroll 2
    for (int k = 0; k < K_; ++k) {
        const float* e = embed + k * C_;         // wave-uniform -> s_load
        float d0 = 0.f, d1 = 0.f, d2 = 0.f, d3 = 0.f;
#pragma unroll
        for (int c = 0; c < C_; c += 4) {
            d0 += x[c + 0] * e[c + 0];
            d1 += x[c + 1] * e[c + 1];
            d2 += x[c + 2] * e[c + 2];
            d3 += x[c + 3] * e[c + 3];
        }
        float dist = x2 + s_e2[k] - 2.f * ((d0 + d1) + (d2 + d3));
        if (dist < best) { best = dist; bk = k; }   // strict < : first-occurrence tie-break
    }

    atomicAdd(&s_cnt[bk], 1);
    out[OFF_IDX + n] = (float)bk;

    const float* eb = embed + bk * C_;
    float lsum = 0.f;
#pragma unroll
    for (int c = 0; c < C_; ++c) {
        float q = eb[c];
        out[OFF_Q + base + (c << 15)] = q;
        float d = q - x[c];
        lsum += d * d;
    }
    // wave(64) shuffle reduce, then 4 partials via LDS
    for (int o = 32; o > 0; o >>= 1) lsum += __shfl_down(lsum, o, 64);
    if ((t & 63) == 0) s_red[t >> 6] = lsum;
    __syncthreads();
    if (t == 0)
        atomicAdd(&wsf[WS_LOSS], (s_red[0] + s_red[1]) + (s_red[2] + s_red[3]));

    // flush histogram
    for (int kk = t; kk < K_; kk += 256) {
        int v = s_cnt[kk];
        if (v) atomicAdd(&wsi[WS_CNT + kk], v);
    }
}

// ---------------------------------------------------------------------------
// K2: dw accumulation — stream input COALESCED in native [B,C,S] layout,
//     atomicAdd into dw[k][c] (128 KB footprint, lives in L2).
// Block = (b, s-tile of 512). Token indices staged in LDS, reused for all c.
// ---------------------------------------------------------------------------
#define TILE_S 512
__global__ __launch_bounds__(256) void k_dw_atomic(const float* __restrict__ in,
                                                   const float* __restrict__ out,
                                                   float* __restrict__ wsf) {
    __shared__ int lds_k[TILE_S];
    const int t = threadIdx.x;
    const int b = blockIdx.x >> 6;               // 4 batches
    const int st = blockIdx.x & 63;              // 64 s-tiles per batch
    const int s0 = st * TILE_S;

    // stage this tile's code indices (coalesced float reads -> int)
#pragma unroll
    for (int j = t; j < TILE_S; j += 256)
        lds_k[j] = (int)out[OFF_IDX + (b << 15) + s0 + j];
    __syncthreads();

    float* dw = wsf + WS_DW;
    const int base = (b << 21) + s0;
#pragma unroll 2
    for (int c = 0; c < C_; ++c) {
        const int cb = base + (c << 15);
#pragma unroll
        for (int j = t; j < TILE_S; j += 256) {
            const float v = in[cb + j];          // fully coalesced
            atomicAdd(&dw[lds_k[j] * C_ + c], v);
        }
    }
}

// ---------------------------------------------------------------------------
// K3: single block, 512 threads. new_cluster_size, n, perplexity, smoothed,
//     loss finalize.
// ---------------------------------------------------------------------------
__global__ __launch_bounds__(512) void k_stats(const float* __restrict__ cs,
                                               float* __restrict__ out,
                                               float* __restrict__ wsf,
                                               int* __restrict__ wsi) {
    __shared__ float sf[K_];
    const int t = threadIdx.x;

    const int cnt = wsi[WS_CNT + t];
    const float ncs = cs[t] * DECAY_ + ONEM_ * (float)cnt;
    out[OFF_NCS + t] = ncs;

    // n = sum(new_cluster_size)
    sf[t] = ncs;
    __syncthreads();
    for (int o = 256; o > 0; o >>= 1) {
        if (t < o) sf[t] += sf[t + o];
        __syncthreads();
    }
    const float n = sf[0];
    __syncthreads();

    // perplexity
    const float ap = (float)cnt / (float)N_;
    sf[t] = ap * logf(ap + 1e-10f);
    __syncthreads();
    for (int o = 256; o > 0; o >>= 1) {
        if (t < o) sf[t] += sf[t + o];
        __syncthreads();
    }
    if (t == 0) {
        out[OFF_PERP] = expf(-sf[0]);
        out[OFF_LOSS] = 0.25f * wsf[WS_LOSS] / (float)((long long)N_ * C_);
    }

    // smoothed cluster size
    wsf[WS_SMOOTH + t] = n * (ncs + ALPHA_) / (n + (float)K_ * ALPHA_);
}

// ---------------------------------------------------------------------------
// K4: EMA finalize — new_embed_avg & new_embed from dw + smoothed.
// One thread per (k, c).
// ---------------------------------------------------------------------------
__global__ __launch_bounds__(256) void k_ema(const float* __restrict__ embed_avg,
                                             float* __restrict__ out,
                                             const float* __restrict__ wsf) {
    const int i = blockIdx.x * 256 + threadIdx.x;   // i = k*64 + c
    const int k = i >> 6;
    const float nea = embed_avg[i] * DECAY_ + ONEM_ * wsf[WS_DW + i];
    out[OFF_NEA + i] = nea;
    out[OFF_NEMB + i] = nea / wsf[WS_SMOOTH + k];
}

extern "C" void kernel_launch(void* const* d_in, const int* in_sizes, int n_in,
                              void* d_out, int out_size, void* d_ws, size_t ws_size,
                              hipStream_t stream) {
    const float* in        = (const float*)d_in[0];
    const float* embed     = (const float*)d_in[1];
    const float* embed_avg = (const float*)d_in[2];
    const float* cs        = (const float*)d_in[3];
    float* out = (float*)d_out;
    float* wsf = (float*)d_ws;
    int*   wsi = (int*)d_ws;

    // zero: loss accum + counts + dw table (ws is re-poisoned 0xAA each call)
    hipMemsetAsync(d_ws, 0, (WS_DW + K_ * C_) * sizeof(float), stream);

    k_assign<<<N_ / 256, 256, 0, stream>>>(in, embed, out, wsf, wsi);
    k_dw_atomic<<<256, 256, 0, stream>>>(in, out, wsf);
    k_stats<<<1, K_, 0, stream>>>(cs, out, wsf, wsi);
    k_ema<<<K_ * C_ / 256, 256, 0, stream>>>(embed_avg, out, wsf);
}

// Round 3
// 766.016 us; speedup vs baseline: 2.6923x; 2.6923x over previous
//
#include <hip/hip_runtime.h>
#include <math.h>

// Problem constants
#define B_    4
#define C_    64
#define S_    32768          // 32*32*32 spatial
#define N_    131072         // B_*S_ tokens
#define K_    512            // codebook size
#define DECAY_ 0.99f
#define ONEM_  0.01f         // 1-DECAY
#define ALPHA_ 1e-5f

// d_out layout (float32, concatenated in reference return order)
#define OFF_LOSS 0
#define OFF_Q    1
#define OFF_PERP 8388609
#define OFF_IDX  8388610
#define OFF_NEMB 8519682
#define OFF_NCS  8552450
#define OFF_NEA  8552962

// ws layout in 4-byte units (total ~533 KB, same as R1 which fit)
#define WS_LOSS   0
#define WS_CNT    16        // 512 ints
#define WS_CUR    528       // 512 ints (scatter cursors)
#define WS_OFFS   1040      // 512 ints (exclusive prefix)
#define WS_SMOOTH 1552      // 512 floats
#define WS_SORT   2064      // 131072 ints (token ids sorted by code)

// ---------------------------------------------------------------------------
// K1: per-token argmin over 512 codes, LDS histogram, loss partial (= best
//     distance), and write flat_x (channel-last [N,64]) into the quantized
//     output region — it is consumed by k_dw and overwritten by k_quant.
// ---------------------------------------------------------------------------
__global__ __launch_bounds__(256) void k_assign(const float* __restrict__ in,
                                                const float* __restrict__ embed,
                                                float* __restrict__ out,
                                                float* __restrict__ wsf,
                                                int* __restrict__ wsi) {
    __shared__ float s_e2[K_];
    __shared__ int   s_cnt[K_];
    __shared__ float s_red[4];

    const int t = threadIdx.x;
    const int n = blockIdx.x * 256 + t;          // token id, channel-last order
    const int b = n >> 15;
    const int s = n & (S_ - 1);
    const int base = (b << 21) + s;              // element index at c=0

    float x[C_];
#pragma unroll
    for (int c = 0; c < C_; ++c) x[c] = in[base + (c << 15)];
    float x2 = 0.f;
#pragma unroll
    for (int c = 0; c < C_; ++c) x2 += x[c] * x[c];

    // cooperative: code norms into LDS, zero histogram
    for (int kk = t; kk < K_; kk += 256) {
        const float4* er = (const float4*)(embed + kk * C_);
        float e2 = 0.f;
#pragma unroll
        for (int q = 0; q < 16; ++q) {
            float4 v = er[q];
            e2 += v.x * v.x + v.y * v.y + v.z * v.z + v.w * v.w;
        }
        s_e2[kk] = e2;
        s_cnt[kk] = 0;
    }
    __syncthreads();

    float best = 3.4e38f;
    int bk = 0;
#pragma unroll 2
    for (int k = 0; k < K_; ++k) {
        const float* e = embed + k * C_;         // wave-uniform -> s_load
        float d0 = 0.f, d1 = 0.f, d2 = 0.f, d3 = 0.f;
#pragma unroll
        for (int c = 0; c < C_; c += 4) {
            d0 += x[c + 0] * e[c + 0];
            d1 += x[c + 1] * e[c + 1];
            d2 += x[c + 2] * e[c + 2];
            d3 += x[c + 3] * e[c + 3];
        }
        float dist = x2 + s_e2[k] - 2.f * ((d0 + d1) + (d2 + d3));
        if (dist < best) { best = dist; bk = k; }   // strict < : first-occurrence tie-break
    }

    atomicAdd(&s_cnt[bk], 1);
    out[OFF_IDX + n] = (float)bk;

    // flat_x row (256 B contiguous) into the quantized region
    float4* dst = (float4*)(out + OFF_Q + (size_t)n * C_);
#pragma unroll
    for (int q = 0; q < 16; ++q)
        dst[q] = make_float4(x[4*q], x[4*q+1], x[4*q+2], x[4*q+3]);

    // loss partial: ||q - x||^2 == best distance (mathematically identical)
    float lsum = best;
    for (int o = 32; o > 0; o >>= 1) lsum += __shfl_down(lsum, o, 64);
    if ((t & 63) == 0) s_red[t >> 6] = lsum;
    __syncthreads();
    if (t == 0)
        atomicAdd(&wsf[WS_LOSS], (s_red[0] + s_red[1]) + (s_red[2] + s_red[3]));

    // flush histogram
    for (int kk = t; kk < K_; kk += 256) {
        int v = s_cnt[kk];
        if (v) atomicAdd(&wsi[WS_CNT + kk], v);
    }
}

// ---------------------------------------------------------------------------
// K2: single block, 512 threads. new_cluster_size, n, perplexity, smoothed,
//     exclusive prefix sum of counts, loss finalize.
// ---------------------------------------------------------------------------
__global__ __launch_bounds__(512) void k_stats(const float* __restrict__ cs,
                                               float* __restrict__ out,
                                               float* __restrict__ wsf,
                                               int* __restrict__ wsi) {
    __shared__ float sf[K_];
    __shared__ int   si[K_];
    const int t = threadIdx.x;

    const int cnt = wsi[WS_CNT + t];
    const float ncs = cs[t] * DECAY_ + ONEM_ * (float)cnt;
    out[OFF_NCS + t] = ncs;

    sf[t] = ncs;
    __syncthreads();
    for (int o = 256; o > 0; o >>= 1) {
        if (t < o) sf[t] += sf[t + o];
        __syncthreads();
    }
    const float n = sf[0];
    __syncthreads();

    const float ap = (float)cnt / (float)N_;
    sf[t] = ap * logf(ap + 1e-10f);
    __syncthreads();
    for (int o = 256; o > 0; o >>= 1) {
        if (t < o) sf[t] += sf[t + o];
        __syncthreads();
    }
    if (t == 0) {
        out[OFF_PERP] = expf(-sf[0]);
        out[OFF_LOSS] = 0.25f * wsf[WS_LOSS] / (float)((long long)N_ * C_);
    }

    wsf[WS_SMOOTH + t] = n * (ncs + ALPHA_) / (n + (float)K_ * ALPHA_);

    // inclusive prefix sum (Hillis-Steele) -> exclusive offsets
    si[t] = cnt;
    __syncthreads();
    for (int o = 1; o < K_; o <<= 1) {
        int v = (t >= o) ? si[t - o] : 0;
        __syncthreads();
        si[t] += v;
        __syncthreads();
    }
    wsi[WS_OFFS + t] = si[t] - cnt;
}

// ---------------------------------------------------------------------------
// K3: counting-sort scatter of token ids by code.
// ---------------------------------------------------------------------------
__global__ __launch_bounds__(256) void k_scatter(const float* __restrict__ out,
                                                 int* __restrict__ wsi) {
    const int n = blockIdx.x * 256 + threadIdx.x;
    const int k = (int)out[OFF_IDX + n];
    const int pos = atomicAdd(&wsi[WS_CUR + k], 1);
    wsi[WS_SORT + wsi[WS_OFFS + k] + pos] = n;
}

// ---------------------------------------------------------------------------
// K4: one block per code. Gather flat_x rows (coalesced 256 B each, token
//     wave-uniform), sum dw, then fused EMA outputs.
// ---------------------------------------------------------------------------
__global__ __launch_bounds__(256) void k_dw(const float* __restrict__ embed_avg,
                                            float* __restrict__ out,
                                            const float* __restrict__ wsf,
                                            const int* __restrict__ wsi) {
    __shared__ float sm[256];
    const int k = blockIdx.x;
    const int t = threadIdx.x;
    const int c = t & 63;
    const int g = t >> 6;                // wave id (0..3), wave-uniform
    const int off = wsi[WS_OFFS + k];
    const int cnt = wsi[WS_CNT + k];
    const float* fx = out + OFF_Q;

    float acc = 0.f;
    for (int j = g; j < cnt; j += 4) {
        const int tok = wsi[WS_SORT + off + j];        // wave-uniform -> s_load
        acc += fx[(size_t)tok * C_ + c];               // 64 lanes = 256 B coalesced
    }
    sm[t] = acc;
    __syncthreads();
    if (t < 64) {
        const float dw = (sm[t] + sm[t + 64]) + (sm[t + 128] + sm[t + 192]);
        const float nea = embed_avg[k * C_ + t] * DECAY_ + ONEM_ * dw;
        out[OFF_NEA + k * C_ + t] = nea;
        out[OFF_NEMB + k * C_ + t] = nea / wsf[WS_SMOOTH + k];
    }
}

// ---------------------------------------------------------------------------
// K5: rewrite the quantized region with embed[idx] in [B,C,S] layout.
//     Stores are coalesced per channel; embed rows are L1-hot float4 reads.
// ---------------------------------------------------------------------------
__global__ __launch_bounds__(256) void k_quant(const float* __restrict__ embed,
                                               float* __restrict__ out) {
    const int t = threadIdx.x;
    const int n = blockIdx.x * 256 + t;
    const int b = n >> 15;
    const int s = n & (S_ - 1);
    const int base = (b << 21) + s;
    const int k = (int)out[OFF_IDX + n];
    const float4* er = (const float4*)(embed + k * C_);
#pragma unroll
    for (int q = 0; q < 16; ++q) {
        float4 v = er[q];
        out[OFF_Q + base + ((4*q + 0) << 15)] = v.x;
        out[OFF_Q + base + ((4*q + 1) << 15)] = v.y;
        out[OFF_Q + base + ((4*q + 2) << 15)] = v.z;
        out[OFF_Q + base + ((4*q + 3) << 15)] = v.w;
    }
}

extern "C" void kernel_launch(void* const* d_in, const int* in_sizes, int n_in,
                              void* d_out, int out_size, void* d_ws, size_t ws_size,
                              hipStream_t stream) {
    const float* in        = (const float*)d_in[0];
    const float* embed     = (const float*)d_in[1];
    const float* embed_avg = (const float*)d_in[2];
    const float* cs        = (const float*)d_in[3];
    float* out = (float*)d_out;
    float* wsf = (float*)d_ws;
    int*   wsi = (int*)d_ws;

    // zero: loss accum + counts + cursors (ws is re-poisoned 0xAA each call)
    hipMemsetAsync(d_ws, 0, (WS_CUR + K_) * sizeof(int), stream);

    k_assign <<<N_ / 256, 256, 0, stream>>>(in, embed, out, wsf, wsi);
    k_stats  <<<1, K_, 0, stream>>>(cs, out, wsf, wsi);
    k_scatter<<<N_ / 256, 256, 0, stream>>>(out, wsi);
    k_dw     <<<K_, 256, 0, stream>>>(embed_avg, out, wsf, wsi);
    k_quant  <<<N_ / 256, 256, 0, stream>>>(embed, out);
}

// Round 4
// 343.531 us; speedup vs baseline: 6.0035x; 2.2298x over previous
//
#include <hip/hip_runtime.h>
#include <math.h>

// Problem constants
#define B_    4
#define C_    64
#define S_    32768          // 32*32*32 spatial
#define N_    131072         // B_*S_ tokens
#define K_    512            // codebook size
#define SPLITS 16            // blocks per code in k_dw
#define DECAY_ 0.99f
#define ONEM_  0.01f         // 1-DECAY
#define ALPHA_ 1e-5f

// d_out layout (float32, concatenated in reference return order)
#define OFF_LOSS 0
#define OFF_Q    1
#define OFF_PERP 8388609
#define OFF_IDX  8388610
#define OFF_NEMB 8519682
#define OFF_NCS  8552450
#define OFF_NEA  8552962

// ws layout in 4-byte units (total ~2.6 MB)
#define WS_LOSS   0
#define WS_CNT    16        // 512 ints
#define WS_CUR    528       // 512 ints (scatter cursors)
#define WS_OFFS   1040      // 512 ints (exclusive prefix)
#define WS_SMOOTH 1552      // 512 floats
#define WS_SORT   2064      // 131072 ints (token ids sorted by code)
#define WS_PART   133136    // 512*16*64 floats (per-split partial dw rows)

// ---------------------------------------------------------------------------
// K1: per-token argmin over 512 codes, LDS histogram, loss partial (= best
//     distance), and write flat_x (channel-last [N,64]) into the quantized
//     output region — consumed by k_dw_split, overwritten later by k_quant.
// ---------------------------------------------------------------------------
__global__ __launch_bounds__(256) void k_assign(const float* __restrict__ in,
                                                const float* __restrict__ embed,
                                                float* __restrict__ out,
                                                float* __restrict__ wsf,
                                                int* __restrict__ wsi) {
    __shared__ float s_e2[K_];
    __shared__ int   s_cnt[K_];
    __shared__ float s_red[4];

    const int t = threadIdx.x;
    const int n = blockIdx.x * 256 + t;          // token id, channel-last order
    const int b = n >> 15;
    const int s = n & (S_ - 1);
    const int base = (b << 21) + s;              // element index at c=0

    float x[C_];
#pragma unroll
    for (int c = 0; c < C_; ++c) x[c] = in[base + (c << 15)];
    float x2 = 0.f;
#pragma unroll
    for (int c = 0; c < C_; ++c) x2 += x[c] * x[c];

    // cooperative: code norms into LDS, zero histogram
    for (int kk = t; kk < K_; kk += 256) {
        const float4* er = (const float4*)(embed + kk * C_);
        float e2 = 0.f;
#pragma unroll
        for (int q = 0; q < 16; ++q) {
            float4 v = er[q];
            e2 += v.x * v.x + v.y * v.y + v.z * v.z + v.w * v.w;
        }
        s_e2[kk] = e2;
        s_cnt[kk] = 0;
    }
    __syncthreads();

    float best = 3.4e38f;
    int bk = 0;
#pragma unroll 2
    for (int k = 0; k < K_; ++k) {
        const float* e = embed + k * C_;         // wave-uniform -> s_load
        float d0 = 0.f, d1 = 0.f, d2 = 0.f, d3 = 0.f;
#pragma unroll
        for (int c = 0; c < C_; c += 4) {
            d0 += x[c + 0] * e[c + 0];
            d1 += x[c + 1] * e[c + 1];
            d2 += x[c + 2] * e[c + 2];
            d3 += x[c + 3] * e[c + 3];
        }
        float dist = x2 + s_e2[k] - 2.f * ((d0 + d1) + (d2 + d3));
        if (dist < best) { best = dist; bk = k; }   // strict < : first-occurrence tie-break
    }

    atomicAdd(&s_cnt[bk], 1);
    out[OFF_IDX + n] = (float)bk;

    // flat_x row (256 B contiguous) into the quantized region
    float4* dst = (float4*)(out + OFF_Q + (size_t)n * C_);
#pragma unroll
    for (int q = 0; q < 16; ++q)
        dst[q] = make_float4(x[4*q], x[4*q+1], x[4*q+2], x[4*q+3]);

    // loss partial: ||q - x||^2 == best distance (mathematically identical)
    float lsum = best;
    for (int o = 32; o > 0; o >>= 1) lsum += __shfl_down(lsum, o, 64);
    if ((t & 63) == 0) s_red[t >> 6] = lsum;
    __syncthreads();
    if (t == 0)
        atomicAdd(&wsf[WS_LOSS], (s_red[0] + s_red[1]) + (s_red[2] + s_red[3]));

    // flush histogram
    for (int kk = t; kk < K_; kk += 256) {
        int v = s_cnt[kk];
        if (v) atomicAdd(&wsi[WS_CNT + kk], v);
    }
}

// ---------------------------------------------------------------------------
// K2: single block, 512 threads. new_cluster_size, n, perplexity, smoothed,
//     exclusive prefix sum of counts, loss finalize.
// ---------------------------------------------------------------------------
__global__ __launch_bounds__(512) void k_stats(const float* __restrict__ cs,
                                               float* __restrict__ out,
                                               float* __restrict__ wsf,
                                               int* __restrict__ wsi) {
    __shared__ float sf[K_];
    __shared__ int   si[K_];
    const int t = threadIdx.x;

    const int cnt = wsi[WS_CNT + t];
    const float ncs = cs[t] * DECAY_ + ONEM_ * (float)cnt;
    out[OFF_NCS + t] = ncs;

    sf[t] = ncs;
    __syncthreads();
    for (int o = 256; o > 0; o >>= 1) {
        if (t < o) sf[t] += sf[t + o];
        __syncthreads();
    }
    const float n = sf[0];
    __syncthreads();

    const float ap = (float)cnt / (float)N_;
    sf[t] = ap * logf(ap + 1e-10f);
    __syncthreads();
    for (int o = 256; o > 0; o >>= 1) {
        if (t < o) sf[t] += sf[t + o];
        __syncthreads();
    }
    if (t == 0) {
        out[OFF_PERP] = expf(-sf[0]);
        out[OFF_LOSS] = 0.25f * wsf[WS_LOSS] / (float)((long long)N_ * C_);
    }

    wsf[WS_SMOOTH + t] = n * (ncs + ALPHA_) / (n + (float)K_ * ALPHA_);

    // inclusive prefix sum (Hillis-Steele) -> exclusive offsets
    si[t] = cnt;
    __syncthreads();
    for (int o = 1; o < K_; o <<= 1) {
        int v = (t >= o) ? si[t - o] : 0;
        __syncthreads();
        si[t] += v;
        __syncthreads();
    }
    wsi[WS_OFFS + t] = si[t] - cnt;
}

// ---------------------------------------------------------------------------
// K3: counting-sort scatter of token ids by code.
// ---------------------------------------------------------------------------
__global__ __launch_bounds__(256) void k_scatter(const float* __restrict__ out,
                                                 int* __restrict__ wsi) {
    const int n = blockIdx.x * 256 + threadIdx.x;
    const int k = (int)out[OFF_IDX + n];
    const int pos = atomicAdd(&wsi[WS_CUR + k], 1);
    wsi[WS_SORT + wsi[WS_OFFS + k] + pos] = n;
}

// ---------------------------------------------------------------------------
// K4: dw partials. Grid = K_*SPLITS one-wave blocks; block (k,p) sums its
//     1/SPLITS share of code k's tokens. Token ids bulk-loaded (1 coalesced
//     load per 64), broadcast via shfl; row gathers issued 4 deep.
//     Partial written with plain coalesced stores (no atomics).
// ---------------------------------------------------------------------------
__global__ __launch_bounds__(64) void k_dw_split(float* __restrict__ out,
                                                 float* __restrict__ wsf,
                                                 const int* __restrict__ wsi) {
    const int lane = threadIdx.x;                 // == channel c
    const int k = blockIdx.x >> 4;
    const int p = blockIdx.x & (SPLITS - 1);
    const int off = wsi[WS_OFFS + k];
    const int cnt = wsi[WS_CNT + k];
    const int chunk = (cnt + SPLITS - 1) >> 4;
    const int j0 = p * chunk;
    const int j1 = min(j0 + chunk, cnt);
    const float* fx = out + OFF_Q;
    const int* sort = wsi + WS_SORT + off;

    float acc = 0.f;
    for (int base = j0; base < j1; base += 64) {
        const int mcnt = min(64, j1 - base);
        int id = 0;
        if (base + lane < j1) id = sort[base + lane];   // one coalesced load
        int m = 0;
        for (; m + 4 <= mcnt; m += 4) {
            const int t0 = __shfl(id, m + 0, 64);
            const int t1 = __shfl(id, m + 1, 64);
            const int t2 = __shfl(id, m + 2, 64);
            const int t3 = __shfl(id, m + 3, 64);
            const float v0 = fx[(size_t)t0 * C_ + lane];  // 4 independent
            const float v1 = fx[(size_t)t1 * C_ + lane];  // 256 B coalesced
            const float v2 = fx[(size_t)t2 * C_ + lane];  // gathers in flight
            const float v3 = fx[(size_t)t3 * C_ + lane];
            acc += (v0 + v1) + (v2 + v3);
        }
        for (; m < mcnt; ++m) {
            const int tk = __shfl(id, m, 64);
            acc += fx[(size_t)tk * C_ + lane];
        }
    }
    wsf[WS_PART + (size_t)blockIdx.x * C_ + lane] = acc;  // plain store
}

// ---------------------------------------------------------------------------
// K5: reduce SPLITS partials -> dw, then EMA outputs new_embed_avg/new_embed.
// ---------------------------------------------------------------------------
__global__ __launch_bounds__(256) void k_ema(const float* __restrict__ embed_avg,
                                             float* __restrict__ out,
                                             const float* __restrict__ wsf) {
    const int i = blockIdx.x * 256 + threadIdx.x;   // i = k*64 + c
    const int k = i >> 6;
    const int c = i & 63;
    float dw = 0.f;
#pragma unroll
    for (int p = 0; p < SPLITS; ++p)
        dw += wsf[WS_PART + (size_t)(k * SPLITS + p) * C_ + c];
    const float nea = embed_avg[i] * DECAY_ + ONEM_ * dw;
    out[OFF_NEA + i] = nea;
    out[OFF_NEMB + i] = nea / wsf[WS_SMOOTH + k];
}

// ---------------------------------------------------------------------------
// K6: rewrite the quantized region with embed[idx] in [B,C,S] layout.
// ---------------------------------------------------------------------------
__global__ __launch_bounds__(256) void k_quant(const float* __restrict__ embed,
                                               float* __restrict__ out) {
    const int t = threadIdx.x;
    const int n = blockIdx.x * 256 + t;
    const int b = n >> 15;
    const int s = n & (S_ - 1);
    const int base = (b << 21) + s;
    const int k = (int)out[OFF_IDX + n];
    const float4* er = (const float4*)(embed + k * C_);
#pragma unroll
    for (int q = 0; q < 16; ++q) {
        float4 v = er[q];
        out[OFF_Q + base + ((4*q + 0) << 15)] = v.x;
        out[OFF_Q + base + ((4*q + 1) << 15)] = v.y;
        out[OFF_Q + base + ((4*q + 2) << 15)] = v.z;
        out[OFF_Q + base + ((4*q + 3) << 15)] = v.w;
    }
}

extern "C" void kernel_launch(void* const* d_in, const int* in_sizes, int n_in,
                              void* d_out, int out_size, void* d_ws, size_t ws_size,
                              hipStream_t stream) {
    const float* in        = (const float*)d_in[0];
    const float* embed     = (const float*)d_in[1];
    const float* embed_avg = (const float*)d_in[2];
    const float* cs        = (const float*)d_in[3];
    float* out = (float*)d_out;
    float* wsf = (float*)d_ws;
    int*   wsi = (int*)d_ws;

    // zero: loss accum + counts + cursors (ws is re-poisoned 0xAA each call)
    hipMemsetAsync(d_ws, 0, (WS_CUR + K_) * sizeof(int), stream);

    k_assign  <<<N_ / 256, 256, 0, stream>>>(in, embed, out, wsf, wsi);
    k_stats   <<<1, K_, 0, stream>>>(cs, out, wsf, wsi);
    k_scatter <<<N_ / 256, 256, 0, stream>>>(out, wsi);
    k_dw_split<<<K_ * SPLITS, 64, 0, stream>>>(out, wsf, wsi);
    k_ema     <<<K_ * C_ / 256, 256, 0, stream>>>(embed_avg, out, wsf);
    k_quant   <<<N_ / 256, 256, 0, stream>>>(embed, out);
}